// Round 1
// baseline (188.745 us; speedup 1.0000x reference)
//
#include <hip/hip_runtime.h>

// Problem constants
#define B_   16
#define C_   256
#define N_   4096   // H*W
#define NH_  8
#define D_   512    // N_/NH_
#define BH_  128    // B_*NH_

typedef __bf16  bf16x8  __attribute__((ext_vector_type(8)));
typedef __bf16  bf16x4  __attribute__((ext_vector_type(4)));
typedef float   floatx4 __attribute__((ext_vector_type(4)));

// XOR swizzle of 8-element column blocks within a 64-wide bf16 LDS row
__device__ __forceinline__ int sw(int row, int kb) { return kb ^ (row & 7); }

// ---------------------------------------------------------------------------
// Kernel 0: x (fp32, [b][c][n]) -> Xt (bf16, [bh][d][c]) transpose + convert.
// grid (N_/64, C_/64, B_), block 256.
// ---------------------------------------------------------------------------
__global__ __launch_bounds__(256) void k_transpose(const float* __restrict__ x,
                                                   __bf16* __restrict__ xt) {
    __shared__ float til[64][65];
    const int n0 = blockIdx.x * 64;
    const int c0 = blockIdx.y * 64;
    const int b  = blockIdx.z;
    const int tc = threadIdx.x & 63;  // col within tile (n on read, c on write)
    const int tr = threadIdx.x >> 6;  // 0..3

    const float* xp = x + ((size_t)b * C_ + c0) * (size_t)N_ + n0;
    for (int p = 0; p < 16; ++p) {
        int c = tr + p * 4;
        til[c][tc] = xp[(size_t)c * N_ + tc];
    }
    __syncthreads();

    const int h  = n0 >> 9;    // n0 / 512
    const int d0 = n0 & 511;
    __bf16* xtp = xt + (((size_t)(b * NH_ + h) * D_ + d0) * C_) + c0;
    for (int p = 0; p < 16; ++p) {
        int d = tr + p * 4;
        xtp[(size_t)d * C_ + tc] = (__bf16)til[tc][d];
    }
}

// ---------------------------------------------------------------------------
// Kernel 1: energy = X X^T per head, fused softmax(rowmax - e) = exp(rowmin-e)/sum.
// grid 512 (= BH_ * 4 row-tiles), block 256 (4 waves, each 64x64 of a 64x256 tile).
// Writes attention (bf16) [bh][c][k], pitch 256.
// ---------------------------------------------------------------------------
__global__ __launch_bounds__(256) void k_energy_softmax(const float* __restrict__ x,
                                                        __bf16* __restrict__ attn) {
    const int bh = blockIdx.x >> 2;
    const int mt = blockIdx.x & 3;
    const int b  = bh >> 3, h = bh & 7;
    const float* xh = x + (size_t)b * C_ * N_ + (size_t)h * D_;  // row pitch N_
    const int c0 = mt * 64;

    __shared__ __bf16 As[64][64];    // A tile: c-rows x k       (8 KB)
    __shared__ __bf16 Bs[256][64];   // B tile: all 256 ck-rows  (32 KB)
    __shared__ float  red[4][64];
    __shared__ float  rminf[64];
    __shared__ float  rsumf[64];

    const int t = threadIdx.x;
    const int wave = t >> 6, lane = t & 63;
    const int q = lane >> 4, l15 = lane & 15;

    floatx4 acc[4][4] = {};

    for (int k0 = 0; k0 < D_; k0 += 64) {
        // stage A: 64 rows x 64 k (fp32 -> bf16), 4 float4 per thread
        for (int p = 0; p < 4; ++p) {
            int idx = p * 256 + t;
            int row = idx >> 4;
            int cb4 = idx & 15;
            float4 v = *(const float4*)(xh + (size_t)(c0 + row) * N_ + k0 + cb4 * 4);
            bf16x4 w;
            w[0] = (__bf16)v.x; w[1] = (__bf16)v.y; w[2] = (__bf16)v.z; w[3] = (__bf16)v.w;
            *(bf16x4*)&As[row][sw(row, cb4 >> 1) * 8 + (cb4 & 1) * 4] = w;
        }
        // stage B: 256 rows x 64 k, 16 float4 per thread
        for (int p = 0; p < 16; ++p) {
            int idx = p * 256 + t;
            int row = idx >> 4;
            int cb4 = idx & 15;
            float4 v = *(const float4*)(xh + (size_t)row * N_ + k0 + cb4 * 4);
            bf16x4 w;
            w[0] = (__bf16)v.x; w[1] = (__bf16)v.y; w[2] = (__bf16)v.z; w[3] = (__bf16)v.w;
            *(bf16x4*)&Bs[row][sw(row, cb4 >> 1) * 8 + (cb4 & 1) * 4] = w;
        }
        __syncthreads();
        for (int kk = 0; kk < 2; ++kk) {
            bf16x8 af[4], bfv[4];
            for (int rt = 0; rt < 4; ++rt) {
                int row = rt * 16 + l15;
                af[rt] = *(const bf16x8*)&As[row][sw(row, kk * 4 + q) * 8];
            }
            for (int ct = 0; ct < 4; ++ct) {
                int row = wave * 64 + ct * 16 + l15;   // n = ck channel
                bfv[ct] = *(const bf16x8*)&Bs[row][sw(row, kk * 4 + q) * 8];
            }
            for (int rt = 0; rt < 4; ++rt)
                for (int ct = 0; ct < 4; ++ct)
                    acc[rt][ct] = __builtin_amdgcn_mfma_f32_16x16x32_bf16(
                        af[rt], bfv[ct], acc[rt][ct], 0, 0, 0);
        }
        __syncthreads();
    }

    // ---- softmax: p = exp(rowmin - e), attn = p / rowsum ----
    // row of acc[rt][ct][r] (within WG's 64 rows) = rt*16 + q*4 + r; col = wave*64 + ct*16 + l15
    float rm[4][4];
    for (int rt = 0; rt < 4; ++rt)
        for (int r = 0; r < 4; ++r) {
            float m = fminf(fminf(acc[rt][0][r], acc[rt][1][r]),
                            fminf(acc[rt][2][r], acc[rt][3][r]));
            m = fminf(m, __shfl_xor(m, 1));
            m = fminf(m, __shfl_xor(m, 2));
            m = fminf(m, __shfl_xor(m, 4));
            m = fminf(m, __shfl_xor(m, 8));
            rm[rt][r] = m;   // min over this wave's 64 cols, replicated in 16-lane group
        }
    if (l15 == 0)
        for (int rt = 0; rt < 4; ++rt)
            for (int r = 0; r < 4; ++r)
                red[wave][rt * 16 + q * 4 + r] = rm[rt][r];
    __syncthreads();
    if (t < 64)
        rminf[t] = fminf(fminf(red[0][t], red[1][t]), fminf(red[2][t], red[3][t]));
    __syncthreads();

    float sm[4][4];
    for (int rt = 0; rt < 4; ++rt)
        for (int r = 0; r < 4; ++r) {
            float rmv = rminf[rt * 16 + q * 4 + r];
            float s = 0.f;
            for (int ct = 0; ct < 4; ++ct) {
                float p = __expf(rmv - acc[rt][ct][r]);
                acc[rt][ct][r] = p;
                s += p;
            }
            s += __shfl_xor(s, 1);
            s += __shfl_xor(s, 2);
            s += __shfl_xor(s, 4);
            s += __shfl_xor(s, 8);
            sm[rt][r] = s;
        }
    if (l15 == 0)
        for (int rt = 0; rt < 4; ++rt)
            for (int r = 0; r < 4; ++r)
                red[wave][rt * 16 + q * 4 + r] = sm[rt][r];
    __syncthreads();
    if (t < 64)
        rsumf[t] = red[0][t] + red[1][t] + red[2][t] + red[3][t];
    __syncthreads();

    __bf16* ap = attn + ((size_t)bh * C_ + c0) * C_;
    for (int rt = 0; rt < 4; ++rt)
        for (int r = 0; r < 4; ++r) {
            int row = rt * 16 + q * 4 + r;
            float inv = 1.0f / rsumf[row];
            for (int ct = 0; ct < 4; ++ct) {
                int col = wave * 64 + ct * 16 + l15;
                ap[(size_t)row * C_ + col] = (__bf16)(acc[rt][ct][r] * inv);
            }
        }
}

// ---------------------------------------------------------------------------
// Kernel 2: out = attn @ X per head, y = gamma*out + x.
// grid 1024 (= BH_ * 2 mtiles * 4 ntiles), block 256 (4 waves in 2x2, each 64x64).
// B operand comes from Xt[bh][d][c] so fragments read contiguous k (=c).
// ---------------------------------------------------------------------------
__global__ __launch_bounds__(256) void k_out(const __bf16* __restrict__ attn,
                                             const __bf16* __restrict__ xt,
                                             const float* __restrict__ x,
                                             const float* __restrict__ gamma,
                                             float* __restrict__ y) {
    const int id = blockIdx.x;
    const int nt = id & 3;
    const int mt = (id >> 2) & 1;
    const int bh = id >> 3;
    const int b  = bh >> 3, h = bh & 7;
    const int c0 = mt * 128, d0 = nt * 128;

    __shared__ __bf16 As[128][64];  // attn rows (c) x k(=ck)   16 KB
    __shared__ __bf16 Bs[128][64];  // Xt rows (d) x k(=ck)     16 KB

    const __bf16* ap = attn + (size_t)bh * C_ * C_;   // pitch C_
    const __bf16* bp = xt   + (size_t)bh * D_ * C_;   // pitch C_

    const int t = threadIdx.x;
    const int wave = t >> 6, lane = t & 63;
    const int q = lane >> 4, l15 = lane & 15;
    const int wy = wave >> 1, wx = wave & 1;

    floatx4 acc[4][4] = {};

    for (int k0 = 0; k0 < C_; k0 += 64) {
        // stage both tiles: 128 rows x 64 k bf16, 4 x bf16x8 per thread each
        for (int p = 0; p < 4; ++p) {
            int idx = p * 256 + t;
            int row = idx >> 3;   // 8 blocks of 8 per row
            int cb  = idx & 7;
            bf16x8 va = *(const bf16x8*)(ap + (size_t)(c0 + row) * C_ + k0 + cb * 8);
            *(bf16x8*)&As[row][sw(row, cb) * 8] = va;
            bf16x8 vb = *(const bf16x8*)(bp + (size_t)(d0 + row) * C_ + k0 + cb * 8);
            *(bf16x8*)&Bs[row][sw(row, cb) * 8] = vb;
        }
        __syncthreads();
        for (int kk = 0; kk < 2; ++kk) {
            bf16x8 af[4], bfv[4];
            for (int rt = 0; rt < 4; ++rt) {
                int row = wy * 64 + rt * 16 + l15;
                af[rt] = *(const bf16x8*)&As[row][sw(row, kk * 4 + q) * 8];
            }
            for (int ct = 0; ct < 4; ++ct) {
                int row = wx * 64 + ct * 16 + l15;  // n = d
                bfv[ct] = *(const bf16x8*)&Bs[row][sw(row, kk * 4 + q) * 8];
            }
            for (int rt = 0; rt < 4; ++rt)
                for (int ct = 0; ct < 4; ++ct)
                    acc[rt][ct] = __builtin_amdgcn_mfma_f32_16x16x32_bf16(
                        af[rt], bfv[ct], acc[rt][ct], 0, 0, 0);
        }
        __syncthreads();
    }

    const float g = *gamma;
    for (int rt = 0; rt < 4; ++rt)
        for (int r = 0; r < 4; ++r) {
            int c = c0 + wy * 64 + rt * 16 + q * 4 + r;
            size_t rowoff = ((size_t)b * C_ + c) * N_ + (size_t)h * D_ + d0 + wx * 64;
            for (int ct = 0; ct < 4; ++ct) {
                int d = ct * 16 + l15;
                y[rowoff + d] = g * acc[rt][ct][r] + x[rowoff + d];
            }
        }
}

// ---------------------------------------------------------------------------
extern "C" void kernel_launch(void* const* d_in, const int* in_sizes, int n_in,
                              void* d_out, int out_size, void* d_ws, size_t ws_size,
                              hipStream_t stream) {
    const float* x     = (const float*)d_in[0];
    const float* gamma = (const float*)d_in[1];
    float*       y     = (float*)d_out;

    // ws layout: Xt bf16 [BH_][D_][C_] (33.5 MB) | attn bf16 [BH_][C_][C_] (16.8 MB)
    __bf16* xt   = (__bf16*)d_ws;
    __bf16* attn = (__bf16*)((char*)d_ws + (size_t)BH_ * D_ * C_ * sizeof(__bf16));

    k_transpose<<<dim3(N_ / 64, C_ / 64, B_), 256, 0, stream>>>(x, xt);
    k_energy_softmax<<<BH_ * 4, 256, 0, stream>>>(x, attn);
    k_out<<<BH_ * 8, 256, 0, stream>>>(attn, xt, x, gamma, y);
}